// Round 8
// baseline (175.937 us; speedup 1.0000x reference)
//
#include <hip/hip_runtime.h>

// NADE forward, B=512, D=1024, H=512, C=4.
// 3-launch structure:
//   1) k_mid   : partial sums A0 (2048 jobs, reads W directly) + V->frag pack
//                (256 jobs) + x->xt and W->WtL transposes (256 jobs) [2560 blk]
//   2) k_prefix: exclusive prefix over chunks, seeded c*log2e
//   3) k_main  : EXACT R0 verified body (79.6us, 52 VGPR)
// R8 change: A0 layout [k][b][h] -> [b][k][h]. k_prefix's walk was a 1 MiB
// pow-2 stride (HBM channel collapse suspect for the ~45us unexplained
// non-main time); now stride 2 KiB, fully sequential per 64 KiB region.
// k_partial reads W rows directly (W[h][d]*L2E bit-identical to stored WtL)
// which breaks the WtL->partial dependency so the W-transpose rides in k_mid.
// Ledger: R3 prefetch spilled; R4/R5 waves-arg=8 -> 32-VGPR budget spill;
// R6 fine-chunks +22us, no occupancy gain. k_main stays at proven schedule.

#define Bv 512
#define Dv 1024
#define Hv 512
#define Cv 4
#define Kv 32
#define DCv 32   // Dv / Kv

#define L2E 1.4426950408889634f
#define LN2 0.6931471805599453f

typedef __attribute__((ext_vector_type(8))) short short8;
typedef __attribute__((ext_vector_type(4))) float f32x4;

__device__ __forceinline__ float fexp2(float x) { return __builtin_amdgcn_exp2f(x); }
__device__ __forceinline__ float flog2(float x) { return __builtin_amdgcn_logf(x); }
__device__ __forceinline__ float frcp(float x)  { return __builtin_amdgcn_rcpf(x); }

// pack two f32 -> bf16x2 by truncation (1 v_perm_b32)
__device__ __forceinline__ unsigned bf16pk(float lo, float hi) {
    return __builtin_amdgcn_perm(__float_as_uint(hi), __float_as_uint(lo), 0x07060302u);
}
__device__ __forceinline__ unsigned short bf16rne(float f) {
    unsigned u = __float_as_uint(f);
    return (unsigned short)((u + 0x7FFFu + ((u >> 16) & 1u)) >> 16);
}

// ---- launch 1: partials + V-pack + both transposes, role-split ----
__global__ __launch_bounds__(512) void k_mid(
        const float* __restrict__ x, const float* __restrict__ V,
        const float* __restrict__ W,
        unsigned short* __restrict__ VtA4, float* __restrict__ WtL,
        float* __restrict__ xt, float* __restrict__ A0) {
    __shared__ __align__(16) char smem[16640];
    const int blk = blockIdx.x;

    if (blk < 2048) {
        // A0[b][k][h] = sum_{d in chunk k} x[b,d]*W[h,d]*L2E
        // (W read directly; W[h][d]*L2E is bit-identical to the WtL value)
        float* xs = (float*)smem;    // [32 d][8 b]
        const int k  = blk >> 6;
        const int bg = blk & 63;
        const int h  = threadIdx.x;
        const int d0 = k * DCv;
        if (threadIdx.x < DCv * 8) {
            int g = threadIdx.x >> 5;   // batch in group of 8
            int j = threadIdx.x & 31;   // d in chunk
            xs[j * 8 + g] = x[(size_t)(bg * 8 + g) * Dv + d0 + j];
        }
        __syncthreads();
        float acc[8];
#pragma unroll
        for (int g = 0; g < 8; ++g) acc[g] = 0.0f;
        const float* wr = W + (size_t)h * Dv + d0;   // 32 contiguous floats
        for (int j = 0; j < DCv; ++j) {
            float wv = wr[j] * L2E;
            const float4 x0 = *(const float4*)(xs + j * 8);
            const float4 x1 = *(const float4*)(xs + j * 8 + 4);
            acc[0] = fmaf(x0.x, wv, acc[0]);
            acc[1] = fmaf(x0.y, wv, acc[1]);
            acc[2] = fmaf(x0.z, wv, acc[2]);
            acc[3] = fmaf(x0.w, wv, acc[3]);
            acc[4] = fmaf(x1.x, wv, acc[4]);
            acc[5] = fmaf(x1.y, wv, acc[5]);
            acc[6] = fmaf(x1.z, wv, acc[6]);
            acc[7] = fmaf(x1.w, wv, acc[7]);
        }
#pragma unroll
        for (int g = 0; g < 8; ++g)
            A0[((size_t)(bg * 8 + g) * Kv + k) * Hv + h] = acc[g];
    } else if (blk < 2304) {
        // V -> VtA4 fragments (bf16 RNE), 4 d per block, 512-thread variant.
        // VtA4[((d*16 + hb)*16 + q*4 + c)*8 + j], elem = V[h=hb*32+q*8+j][d][c]
        unsigned short* tile = (unsigned short*)smem;   // 8192 shorts = 16 KiB
        const int d0  = (blk - 2048) * 4;
        const int dd  = threadIdx.x & 3;
        const int hb0 = threadIdx.x >> 2;   // 0..127 -> 128 h per pass
#pragma unroll
        for (int p = 0; p < 4; ++p) {
            int h = p * 128 + hb0;
            float4 v = *(const float4*)(V + ((size_t)h * Dv + d0 + dd) * Cv);
            int hb = h >> 5, q = (h >> 3) & 3, j = h & 7;
            int base = ((dd * 16 + hb) * 16 + q * 4) * 8 + j;
            tile[base + 0 * 8] = bf16rne(v.x);
            tile[base + 1 * 8] = bf16rne(v.y);
            tile[base + 2 * 8] = bf16rne(v.z);
            tile[base + 3 * 8] = bf16rne(v.w);
        }
        __syncthreads();
        uint4* dst = (uint4*)(VtA4 + (size_t)d0 * 2048);
        const uint4* srcp = (const uint4*)tile;
        for (int tt = threadIdx.x; tt < 1024; tt += 512) dst[tt] = srcp[tt];
    } else {
        // transposes: blk-2304 in [0,256): mb=0 -> x->xt, mb=1 -> W->WtL(*L2E)
        float (*t)[65] = (float(*)[65])smem;
        const int t2   = blk - 2304;
        const int mb   = t2 >> 7;            // 0: x, 1: W
        const int tile = t2 & 127;
        const int tr   = tile >> 4;          // src row tile (b/h)
        const int tc   = tile & 15;          // d tile
        const float* src = mb ? W : x;
        float* dst       = mb ? WtL : xt;
        const float scale = mb ? L2E : 1.0f;
        const int lx = threadIdx.x & 15;
        const int ly = threadIdx.x >> 4;     // 0..31
#pragma unroll
        for (int r = 0; r < 64; r += 32) {
            int row = r + ly;
            float4 v = *(const float4*)(src + (size_t)(tr * 64 + row) * Dv + tc * 64 + lx * 4);
            t[row][lx * 4 + 0] = v.x;
            t[row][lx * 4 + 1] = v.y;
            t[row][lx * 4 + 2] = v.z;
            t[row][lx * 4 + 3] = v.w;
        }
        __syncthreads();
#pragma unroll
        for (int r = 0; r < 64; r += 32) {
            int row = r + ly;   // d within tile
            float4 o = make_float4(t[lx * 4 + 0][row] * scale,
                                   t[lx * 4 + 1][row] * scale,
                                   t[lx * 4 + 2][row] * scale,
                                   t[lx * 4 + 3][row] * scale);
            *(float4*)(dst + (size_t)(tc * 64 + row) * 512 + tr * 64 + lx * 4) = o;
        }
    }
}

// ---- launch 2: in-place exclusive prefix over chunks, seeded c*log2e ----
// A0 layout [b][k][h]: per-thread stride is Hv*4B = 2 KiB (was 1 MiB).
__global__ void k_prefix(float* __restrict__ A0, const float* __restrict__ cbias) {
    int gid = blockIdx.x * blockDim.x + threadIdx.x;   // B*H
    int h = gid & (Hv - 1);
    int bi = gid >> 9;
    float run = cbias[h] * L2E;
    float* p = A0 + (size_t)bi * (Kv * Hv) + h;
    for (int k = 0; k < Kv; ++k) {
        float t = p[(size_t)k * Hv];
        p[(size_t)k * Hv] = run;
        run += t;
    }
}

// ---- launch 3: main scan (EXACT R0 verified body; A0 index remapped). ----
__global__ __launch_bounds__(256, 4) void k_main(
        const float* __restrict__ xt, const float* __restrict__ bbias,
        const unsigned short* __restrict__ VtA4, const float* __restrict__ WtL,
        const float* __restrict__ A0, float* __restrict__ out) {
    const int k    = blockIdx.x >> 5;
    const int bg   = blockIdx.x & 31;
    const int wid  = threadIdx.x >> 6;   // H-slice / epilogue role
    const int lane = threadIdx.x & 63;
    const int bl   = lane & 15;          // batch col (B-op) / class row m (A-op)
    const int quad = lane >> 4;
    const int b    = bg * 16 + bl;
    const int d0   = k * DCv;
    const int stp  = wid >> 1;           // which step of the pair this wave stores
    const bool isP = wid & 1;            // y vs p output

    __shared__ f32x4 red[2][2][4][64];   // [pairbuf][step][wid][lane], 16 KiB

    // a state: h = wid*128 + kb*32 + quad*8 + j (scaled domain)
    float a[32];
    {
        const float* ap = A0 + ((size_t)b * Kv + k) * Hv + wid * 128 + quad * 8;
#pragma unroll
        for (int kb = 0; kb < 4; ++kb) {
            float4 t0 = *(const float4*)(ap + kb * 32);
            float4 t1 = *(const float4*)(ap + kb * 32 + 4);
            a[kb*8+0]=t0.x; a[kb*8+1]=t0.y; a[kb*8+2]=t0.z; a[kb*8+3]=t0.w;
            a[kb*8+4]=t1.x; a[kb*8+5]=t1.y; a[kb*8+6]=t1.z; a[kb*8+7]=t1.w;
        }
    }

    const bool act = (bl < 4);
    const unsigned short* vp = VtA4 + (((size_t)d0 * 16 + wid * 4) * 16 + quad * 4 + bl) * 8;
    const float* wp = WtL + (size_t)d0 * Hv + wid * 128 + quad * 8;
    const float* xp = xt + (size_t)d0 * Bv + b;
    const float* bp = bbias + (d0 + stp) * Cv;
    float* sp = out + (isP ? (size_t)Bv * Dv * Cv : (size_t)0)
                    + (size_t)b * Dv * Cv + (d0 + stp) * Cv;

    const short8 zfrag = {0,0,0,0,0,0,0,0};

    for (int i1 = 0; i1 < DCv / 2; ++i1) {
        // fragment / scalar prefetch for both steps of the pair
        short8 afA[4], afB[4];
#pragma unroll
        for (int kb = 0; kb < 4; ++kb)
            afA[kb] = act ? *(const short8*)(vp + kb * 128) : zfrag;
#pragma unroll
        for (int kb = 0; kb < 4; ++kb)
            afB[kb] = act ? *(const short8*)(vp + 2048 + kb * 128) : zfrag;
        float xdA = xp[0];
        float xdB = xp[Bv];
        float4 bbv = *(const float4*)bp;   // this wave's step's bias

        // ---- step A: sigmoid + pack + MFMA ----
        unsigned pkA[16];
#pragma unroll
        for (int m = 0; m < 32; m += 2) {
            float s0 = frcp(1.0f + fexp2(-a[m]));
            float s1 = frcp(1.0f + fexp2(-a[m + 1]));
            pkA[m >> 1] = bf16pk(s0, s1);
        }
        f32x4 accA = {0.f, 0.f, 0.f, 0.f};
#pragma unroll
        for (int kb = 0; kb < 4; ++kb) {
            union { unsigned u[4]; short8 s; } cv;
            cv.u[0] = pkA[kb*4+0]; cv.u[1] = pkA[kb*4+1];
            cv.u[2] = pkA[kb*4+2]; cv.u[3] = pkA[kb*4+3];
            accA = __builtin_amdgcn_mfma_f32_16x16x32_bf16(afA[kb], cv.s, accA, 0, 0, 0);
        }
        // advance a to step B
#pragma unroll
        for (int kb = 0; kb < 4; ++kb)
#pragma unroll
            for (int j = 0; j < 8; ++j)
                a[kb*8+j] = fmaf(xdA, wp[kb*32+j], a[kb*8+j]);

        // ---- step B: sigmoid + pack + MFMA ----
        unsigned pkB[16];
#pragma unroll
        for (int m = 0; m < 32; m += 2) {
            float s0 = frcp(1.0f + fexp2(-a[m]));
            float s1 = frcp(1.0f + fexp2(-a[m + 1]));
            pkB[m >> 1] = bf16pk(s0, s1);
        }
        f32x4 accB = {0.f, 0.f, 0.f, 0.f};
#pragma unroll
        for (int kb = 0; kb < 4; ++kb) {
            union { unsigned u[4]; short8 s; } cv;
            cv.u[0] = pkB[kb*4+0]; cv.u[1] = pkB[kb*4+1];
            cv.u[2] = pkB[kb*4+2]; cv.u[3] = pkB[kb*4+3];
            accB = __builtin_amdgcn_mfma_f32_16x16x32_bf16(afB[kb], cv.s, accB, 0, 0, 0);
        }
        // advance a to next pair
#pragma unroll
        for (int kb = 0; kb < 4; ++kb)
#pragma unroll
            for (int j = 0; j < 8; ++j)
                a[kb*8+j] = fmaf(xdB, wp[Hv + kb*32+j], a[kb*8+j]);

        // ---- cross-wave reduce: one barrier per pair ----
        red[i1 & 1][0][wid][lane] = accA;
        red[i1 & 1][1][wid][lane] = accB;
        __syncthreads();

        f32x4 r0 = red[i1 & 1][stp][0][lane];
        f32x4 r1 = red[i1 & 1][stp][1][lane];
        f32x4 r2 = red[i1 & 1][stp][2][lane];
        f32x4 r3 = red[i1 & 1][stp][3][lane];
        float w0 = r0.x + r1.x + r2.x + r3.x + bbv.x;
        float w1 = r0.y + r1.y + r2.y + r3.y + bbv.y;
        float w2 = r0.z + r1.z + r2.z + r3.z + bbv.z;
        float w3 = r0.w + r1.w + r2.w + r3.w + bbv.w;

        if (!isP) {
            if (quad == 0) *(float4*)sp = make_float4(w0, w1, w2, w3);
        } else {
            float mx = fmaxf(fmaxf(w0, w1), fmaxf(w2, w3));
            float e0 = fexp2((w0 - mx) * L2E);
            float e1 = fexp2((w1 - mx) * L2E);
            float e2 = fexp2((w2 - mx) * L2E);
            float e3 = fexp2((w3 - mx) * L2E);
            float lse = mx + flog2(e0 + e1 + e2 + e3) * LN2;
            if (quad == 0)
                *(float4*)sp = make_float4(w0 - lse, w1 - lse, w2 - lse, w3 - lse);
        }

        vp += 2 * 2048;    // 2 d-steps
        wp += 2 * Hv;
        xp += 2 * Bv;
        bp += 2 * Cv;
        sp += 2 * Cv;
    }
}

extern "C" void kernel_launch(void* const* d_in, const int* in_sizes, int n_in,
                              void* d_out, int out_size, void* d_ws, size_t ws_size,
                              hipStream_t stream) {
    const float* x  = (const float*)d_in[0];   // [B, D]
    const float* V  = (const float*)d_in[1];   // [H, D, C]
    const float* bb = (const float*)d_in[2];   // [D, C]
    const float* W  = (const float*)d_in[3];   // [H, D]
    const float* cb = (const float*)d_in[4];   // [1, H]
    float* out = (float*)d_out;                // y_hat [B*D*C] then p_hat

    char* ws = (char*)d_ws;
    unsigned short* VtA4 = (unsigned short*)ws;                 // 4 MiB
    float* WtL = (float*)(ws + (size_t)4 * 1024 * 1024);        // 2 MiB
    float* xt  = (float*)(ws + (size_t)6 * 1024 * 1024);        // 2 MiB
    float* A0  = (float*)(ws + (size_t)8 * 1024 * 1024);        // 32 MiB (B*K*H)

    k_mid<<<2560, 512, 0, stream>>>(x, V, W, VtA4, WtL, xt, A0);
    k_prefix<<<(Bv * Hv) / 256, 256, 0, stream>>>(A0, cb);
    k_main<<<Kv * 32, 256, 0, stream>>>(xt, bb, VtA4, WtL, A0, out);
}

// Round 9
// 167.356 us; speedup vs baseline: 1.0513x; 1.0513x over previous
//
#include <hip/hip_runtime.h>

// NADE forward, B=512, D=1024, H=512, C=4.
// 4-launch structure (pre-kernels verbatim from verified R7 = 167.6us):
//   1) k_prepW : W -> WtL transpose (*log2e)                 [128 blocks]
//   2) k_mid   : partial sums A0 (2048 jobs) + V->frag pack (256 jobs)
//                + x -> xt transpose (128 jobs), role-split  [2432 blocks]
//   3) k_prefix: exclusive prefix over 32 chunks, seeded c*log2e
//   4) k_main  : QUAD-step scan: 4 d-steps per barrier (8 barriers/chunk,
//                was 16). Wave wid computes its 128-h slice for all 4 steps;
//                after the barrier it finalizes step wid (y AND p). Only one
//                step's V-fragments + one acc live at a time (pressure DROPS
//                vs pair version). All per-element arithmetic bit-identical.
// Ledger: R3 prefetch spilled; R4/R5 waves-arg=8 -> 32-VGPR budget spill;
// R6 fine-chunks +22us no occupancy gain; R8 W-direct reads +7us (line
// amplification), A0 relayout neutral-negative. Grid stays 1024; occupancy
// is grid-bound at 4 waves/SIMD; the remaining lever is barrier count.

#define Bv 512
#define Dv 1024
#define Hv 512
#define Cv 4
#define Kv 32
#define DCv 32   // Dv / Kv

#define L2E 1.4426950408889634f
#define LN2 0.6931471805599453f

typedef __attribute__((ext_vector_type(8))) short short8;
typedef __attribute__((ext_vector_type(4))) float f32x4;

__device__ __forceinline__ float fexp2(float x) { return __builtin_amdgcn_exp2f(x); }
__device__ __forceinline__ float flog2(float x) { return __builtin_amdgcn_logf(x); }
__device__ __forceinline__ float frcp(float x)  { return __builtin_amdgcn_rcpf(x); }

// pack two f32 -> bf16x2 by truncation (1 v_perm_b32)
__device__ __forceinline__ unsigned bf16pk(float lo, float hi) {
    return __builtin_amdgcn_perm(__float_as_uint(hi), __float_as_uint(lo), 0x07060302u);
}
__device__ __forceinline__ unsigned short bf16rne(float f) {
    unsigned u = __float_as_uint(f);
    return (unsigned short)((u + 0x7FFFu + ((u >> 16) & 1u)) >> 16);
}

// ---- launch 1: W -> WtL (transpose, *log2e). 128 tiles of 64x64. ----
__global__ __launch_bounds__(256) void k_prepW(const float* __restrict__ W,
                                               float* __restrict__ WtL) {
    __shared__ float t[64][65];
    const int tile = blockIdx.x;         // 0..127
    const int tr   = tile >> 4;          // h tile, 0..7
    const int tc   = tile & 15;          // d tile, 0..15
    const int lx = threadIdx.x & 15;
    const int ly = threadIdx.x >> 4;
#pragma unroll
    for (int r = 0; r < 64; r += 16) {
        int row = r + ly;
        float4 v = *(const float4*)(W + (size_t)(tr * 64 + row) * Dv + tc * 64 + lx * 4);
        t[row][lx * 4 + 0] = v.x;
        t[row][lx * 4 + 1] = v.y;
        t[row][lx * 4 + 2] = v.z;
        t[row][lx * 4 + 3] = v.w;
    }
    __syncthreads();
#pragma unroll
    for (int r = 0; r < 64; r += 16) {
        int row = r + ly;   // d within tile
        float4 o = make_float4(t[lx * 4 + 0][row] * L2E,
                               t[lx * 4 + 1][row] * L2E,
                               t[lx * 4 + 2][row] * L2E,
                               t[lx * 4 + 3][row] * L2E);
        *(float4*)(WtL + (size_t)(tc * 64 + row) * 512 + tr * 64 + lx * 4) = o;
    }
}

// ---- launch 2: partials + V-pack + x-transpose, role-split by blockIdx ----
__global__ __launch_bounds__(512) void k_mid(
        const float* __restrict__ x, const float* __restrict__ V,
        const float* __restrict__ WtL,
        unsigned short* __restrict__ VtA4, float* __restrict__ xt,
        float* __restrict__ A0) {
    __shared__ __align__(16) char smem[16640];
    const int blk = blockIdx.x;

    if (blk < 2048) {
        // A0[k][b][h] = sum_{d in chunk k} x[b,d]*WtL[d][h]  (verbatim k_partial)
        float* xs = (float*)smem;    // [32 d][8 b]
        const int k  = blk >> 6;
        const int bg = blk & 63;
        const int h  = threadIdx.x;
        const int d0 = k * DCv;
        if (threadIdx.x < DCv * 8) {
            int g = threadIdx.x >> 5;   // batch in group of 8
            int j = threadIdx.x & 31;   // d in chunk
            xs[j * 8 + g] = x[(size_t)(bg * 8 + g) * Dv + d0 + j];
        }
        __syncthreads();
        float acc[8];
#pragma unroll
        for (int g = 0; g < 8; ++g) acc[g] = 0.0f;
        const float* wp = WtL + (size_t)d0 * Hv + h;
        for (int j = 0; j < DCv; ++j) {
            float wv = wp[(size_t)j * Hv];
            const float4 x0 = *(const float4*)(xs + j * 8);
            const float4 x1 = *(const float4*)(xs + j * 8 + 4);
            acc[0] = fmaf(x0.x, wv, acc[0]);
            acc[1] = fmaf(x0.y, wv, acc[1]);
            acc[2] = fmaf(x0.z, wv, acc[2]);
            acc[3] = fmaf(x0.w, wv, acc[3]);
            acc[4] = fmaf(x1.x, wv, acc[4]);
            acc[5] = fmaf(x1.y, wv, acc[5]);
            acc[6] = fmaf(x1.z, wv, acc[6]);
            acc[7] = fmaf(x1.w, wv, acc[7]);
        }
#pragma unroll
        for (int g = 0; g < 8; ++g)
            A0[((size_t)k * Bv + bg * 8 + g) * Hv + h] = acc[g];
    } else if (blk < 2304) {
        // V -> VtA4 fragments (bf16 RNE), 4 d per block, 512-thread variant.
        // VtA4[((d*16 + hb)*16 + q*4 + c)*8 + j], elem = V[h=hb*32+q*8+j][d][c]
        unsigned short* tile = (unsigned short*)smem;   // 8192 shorts = 16 KiB
        const int d0  = (blk - 2048) * 4;
        const int dd  = threadIdx.x & 3;
        const int hb0 = threadIdx.x >> 2;   // 0..127 -> 128 h per pass
#pragma unroll
        for (int p = 0; p < 4; ++p) {
            int h = p * 128 + hb0;
            float4 v = *(const float4*)(V + ((size_t)h * Dv + d0 + dd) * Cv);
            int hb = h >> 5, q = (h >> 3) & 3, j = h & 7;
            int base = ((dd * 16 + hb) * 16 + q * 4) * 8 + j;
            tile[base + 0 * 8] = bf16rne(v.x);
            tile[base + 1 * 8] = bf16rne(v.y);
            tile[base + 2 * 8] = bf16rne(v.z);
            tile[base + 3 * 8] = bf16rne(v.w);
        }
        __syncthreads();
        uint4* dst = (uint4*)(VtA4 + (size_t)d0 * 2048);
        const uint4* srcp = (const uint4*)tile;
        for (int tt = threadIdx.x; tt < 1024; tt += 512) dst[tt] = srcp[tt];
    } else {
        // x -> xt transpose (scale 1), 512-thread variant of the 64x64 tile.
        float (*t)[65] = (float(*)[65])smem;
        const int tile = blk - 2304;         // 0..127
        const int tr   = tile >> 4;          // b tile
        const int tc   = tile & 15;          // d tile
        const int lx = threadIdx.x & 15;
        const int ly = threadIdx.x >> 4;     // 0..31
#pragma unroll
        for (int r = 0; r < 64; r += 32) {
            int row = r + ly;
            float4 v = *(const float4*)(x + (size_t)(tr * 64 + row) * Dv + tc * 64 + lx * 4);
            t[row][lx * 4 + 0] = v.x;
            t[row][lx * 4 + 1] = v.y;
            t[row][lx * 4 + 2] = v.z;
            t[row][lx * 4 + 3] = v.w;
        }
        __syncthreads();
#pragma unroll
        for (int r = 0; r < 64; r += 32) {
            int row = r + ly;   // d within tile
            float4 o = make_float4(t[lx * 4 + 0][row],
                                   t[lx * 4 + 1][row],
                                   t[lx * 4 + 2][row],
                                   t[lx * 4 + 3][row]);
            *(float4*)(xt + (size_t)(tc * 64 + row) * 512 + tr * 64 + lx * 4) = o;
        }
    }
}

// ---- launch 3: in-place exclusive prefix over chunks, seeded c*log2e ----
__global__ void k_prefix(float* __restrict__ A0, const float* __restrict__ cbias) {
    int gid = blockIdx.x * blockDim.x + threadIdx.x;   // B*H
    int h = gid & (Hv - 1);
    int bi = gid >> 9;
    float run = cbias[h] * L2E;
    float* p = A0 + (size_t)bi * Hv + h;
    for (int k = 0; k < Kv; ++k) {
        float t = p[(size_t)k * Bv * Hv];
        p[(size_t)k * Bv * Hv] = run;
        run += t;
    }
}

// ---- launch 4: main scan, QUAD-step (4 d-steps per barrier). ----
__global__ __launch_bounds__(256, 4) void k_main(
        const float* __restrict__ xt, const float* __restrict__ bbias,
        const unsigned short* __restrict__ VtA4, const float* __restrict__ WtL,
        const float* __restrict__ A0, float* __restrict__ out) {
    const int k    = blockIdx.x >> 5;
    const int bg   = blockIdx.x & 31;
    const int wid  = threadIdx.x >> 6;   // H-slice owner / epilogue-step owner
    const int lane = threadIdx.x & 63;
    const int bl   = lane & 15;          // batch col (B-op) / class row m (A-op)
    const int quad = lane >> 4;
    const int b    = bg * 16 + bl;
    const int d0   = k * DCv;

    __shared__ f32x4 red[2][4][4][64];   // [buf][step][wid][lane], 32 KiB

    // a state: h = wid*128 + kb*32 + quad*8 + j (scaled domain)
    float a[32];
    {
        const float* ap = A0 + ((size_t)k * Bv + b) * Hv + wid * 128 + quad * 8;
#pragma unroll
        for (int kb = 0; kb < 4; ++kb) {
            float4 t0 = *(const float4*)(ap + kb * 32);
            float4 t1 = *(const float4*)(ap + kb * 32 + 4);
            a[kb*8+0]=t0.x; a[kb*8+1]=t0.y; a[kb*8+2]=t0.z; a[kb*8+3]=t0.w;
            a[kb*8+4]=t1.x; a[kb*8+5]=t1.y; a[kb*8+6]=t1.z; a[kb*8+7]=t1.w;
        }
    }

    const bool act = (bl < 4);
    const unsigned short* vp = VtA4 + (((size_t)d0 * 16 + wid * 4) * 16 + quad * 4 + bl) * 8;
    const float* wp = WtL + (size_t)d0 * Hv + wid * 128 + quad * 8;
    const float* xp = xt + (size_t)d0 * Bv + b;
    const float* bp = bbias + (d0 + wid) * Cv;             // epilogue step = wid
    float* spY = out + (size_t)b * Dv * Cv + (d0 + wid) * Cv;
    float* spP = spY + (size_t)Bv * Dv * Cv;

    const short8 zfrag = {0,0,0,0,0,0,0,0};

    for (int i1 = 0; i1 < DCv / 4; ++i1) {
        const int buf = i1 & 1;
#pragma unroll
        for (int s = 0; s < 4; ++s) {
            // this step's fragments + scalar (only one step live at a time)
            short8 af[4];
#pragma unroll
            for (int kb = 0; kb < 4; ++kb)
                af[kb] = act ? *(const short8*)(vp + s * 2048 + kb * 128) : zfrag;
            float xd = xp[s * Bv];

            // sigmoid + pack
            unsigned pk[16];
#pragma unroll
            for (int m = 0; m < 32; m += 2) {
                float s0 = frcp(1.0f + fexp2(-a[m]));
                float s1 = frcp(1.0f + fexp2(-a[m + 1]));
                pk[m >> 1] = bf16pk(s0, s1);
            }
            // MFMA over the wave's 128-h slice
            f32x4 acc = {0.f, 0.f, 0.f, 0.f};
#pragma unroll
            for (int kb = 0; kb < 4; ++kb) {
                union { unsigned u[4]; short8 s8; } cv;
                cv.u[0] = pk[kb*4+0]; cv.u[1] = pk[kb*4+1];
                cv.u[2] = pk[kb*4+2]; cv.u[3] = pk[kb*4+3];
                acc = __builtin_amdgcn_mfma_f32_16x16x32_bf16(af[kb], cv.s8, acc, 0, 0, 0);
            }
            // advance a to next step (same fmaf sequence as pair version)
#pragma unroll
            for (int kb = 0; kb < 4; ++kb)
#pragma unroll
                for (int j = 0; j < 8; ++j)
                    a[kb*8+j] = fmaf(xd, wp[s * Hv + kb*32 + j], a[kb*8+j]);

            red[buf][s][wid][lane] = acc;
        }
        __syncthreads();

        // ---- epilogue: this wave finalizes step 'wid' (y AND p) ----
        {
            float4 bbv = *(const float4*)bp;
            f32x4 r0 = red[buf][wid][0][lane];
            f32x4 r1 = red[buf][wid][1][lane];
            f32x4 r2 = red[buf][wid][2][lane];
            f32x4 r3 = red[buf][wid][3][lane];
            float w0 = r0.x + r1.x + r2.x + r3.x + bbv.x;
            float w1 = r0.y + r1.y + r2.y + r3.y + bbv.y;
            float w2 = r0.z + r1.z + r2.z + r3.z + bbv.z;
            float w3 = r0.w + r1.w + r2.w + r3.w + bbv.w;
            if (quad == 0) {
                *(float4*)spY = make_float4(w0, w1, w2, w3);
                float mx = fmaxf(fmaxf(w0, w1), fmaxf(w2, w3));
                float e0 = fexp2((w0 - mx) * L2E);
                float e1 = fexp2((w1 - mx) * L2E);
                float e2 = fexp2((w2 - mx) * L2E);
                float e3 = fexp2((w3 - mx) * L2E);
                float lse = mx + flog2(e0 + e1 + e2 + e3) * LN2;
                *(float4*)spP = make_float4(w0 - lse, w1 - lse, w2 - lse, w3 - lse);
            }
        }

        vp  += 4 * 2048;   // 4 d-steps
        wp  += 4 * Hv;
        xp  += 4 * Bv;
        bp  += 4 * Cv;
        spY += 4 * Cv;
        spP += 4 * Cv;
    }
}

extern "C" void kernel_launch(void* const* d_in, const int* in_sizes, int n_in,
                              void* d_out, int out_size, void* d_ws, size_t ws_size,
                              hipStream_t stream) {
    const float* x  = (const float*)d_in[0];   // [B, D]
    const float* V  = (const float*)d_in[1];   // [H, D, C]
    const float* bb = (const float*)d_in[2];   // [D, C]
    const float* W  = (const float*)d_in[3];   // [H, D]
    const float* cb = (const float*)d_in[4];   // [1, H]
    float* out = (float*)d_out;                // y_hat [B*D*C] then p_hat

    char* ws = (char*)d_ws;
    unsigned short* VtA4 = (unsigned short*)ws;                 // 4 MiB
    float* WtL = (float*)(ws + (size_t)4 * 1024 * 1024);        // 2 MiB
    float* xt  = (float*)(ws + (size_t)6 * 1024 * 1024);        // 2 MiB
    float* A0  = (float*)(ws + (size_t)8 * 1024 * 1024);        // 32 MiB (K*B*H)

    k_prepW<<<128, 256, 0, stream>>>(W, WtL);
    k_mid<<<2432, 512, 0, stream>>>(x, V, WtL, VtA4, xt, A0);
    k_prefix<<<(Bv * Hv) / 256, 256, 0, stream>>>(A0, cb);
    k_main<<<Kv * 32, 256, 0, stream>>>(xt, bb, VtA4, WtL, A0, out);
}

// Round 10
// 163.926 us; speedup vs baseline: 1.0733x; 1.0209x over previous
//
#include <hip/hip_runtime.h>

// NADE forward, B=512, D=1024, H=512, C=4.
// 4-launch structure (pre-kernels verbatim from verified R7/R9):
//   1) k_prepW : W -> WtL transpose (*log2e)                 [128 blocks]
//   2) k_mid   : partial sums A0 (2048 jobs) + V->frag pack (256 jobs)
//                + x -> xt transpose (128 jobs), role-split  [2432 blocks]
//   3) k_prefix: exclusive prefix over 32 chunks, seeded c*log2e
//   4) k_main  : OCT-step scan: 8 d-steps per barrier (4 barriers/chunk,
//                was 8 in R9, 16 in R7). Key enabler: MFMA C rows 4..15 are
//                zero (A rows 4..15 are zfrag), so only quad==0 lanes carry
//                data -> red stores 16 batches/step, 4x smaller, so the
//                8-step dbuf fits in 16 KiB. Wave wid finalizes steps
//                {2wid, 2wid+1} via lanes 0-15 / 32-47 (y AND p).
// Ledger: R3 prefetch spilled; R4/R5 waves-arg=8 -> 32-VGPR budget spill;
// R6 fine-chunks +22us no occupancy gain; R8 W-direct +7us; R9 quad-step
// -3.4us (barrier cadence is the proven lever). (256,4) = 64-VGPR budget.

#define Bv 512
#define Dv 1024
#define Hv 512
#define Cv 4
#define Kv 32
#define DCv 32   // Dv / Kv

#define L2E 1.4426950408889634f
#define LN2 0.6931471805599453f

typedef __attribute__((ext_vector_type(8))) short short8;
typedef __attribute__((ext_vector_type(4))) float f32x4;

__device__ __forceinline__ float fexp2(float x) { return __builtin_amdgcn_exp2f(x); }
__device__ __forceinline__ float flog2(float x) { return __builtin_amdgcn_logf(x); }
__device__ __forceinline__ float frcp(float x)  { return __builtin_amdgcn_rcpf(x); }

// pack two f32 -> bf16x2 by truncation (1 v_perm_b32)
__device__ __forceinline__ unsigned bf16pk(float lo, float hi) {
    return __builtin_amdgcn_perm(__float_as_uint(hi), __float_as_uint(lo), 0x07060302u);
}
__device__ __forceinline__ unsigned short bf16rne(float f) {
    unsigned u = __float_as_uint(f);
    return (unsigned short)((u + 0x7FFFu + ((u >> 16) & 1u)) >> 16);
}

// ---- launch 1: W -> WtL (transpose, *log2e). 128 tiles of 64x64. ----
__global__ __launch_bounds__(256) void k_prepW(const float* __restrict__ W,
                                               float* __restrict__ WtL) {
    __shared__ float t[64][65];
    const int tile = blockIdx.x;         // 0..127
    const int tr   = tile >> 4;          // h tile, 0..7
    const int tc   = tile & 15;          // d tile, 0..15
    const int lx = threadIdx.x & 15;
    const int ly = threadIdx.x >> 4;
#pragma unroll
    for (int r = 0; r < 64; r += 16) {
        int row = r + ly;
        float4 v = *(const float4*)(W + (size_t)(tr * 64 + row) * Dv + tc * 64 + lx * 4);
        t[row][lx * 4 + 0] = v.x;
        t[row][lx * 4 + 1] = v.y;
        t[row][lx * 4 + 2] = v.z;
        t[row][lx * 4 + 3] = v.w;
    }
    __syncthreads();
#pragma unroll
    for (int r = 0; r < 64; r += 16) {
        int row = r + ly;   // d within tile
        float4 o = make_float4(t[lx * 4 + 0][row] * L2E,
                               t[lx * 4 + 1][row] * L2E,
                               t[lx * 4 + 2][row] * L2E,
                               t[lx * 4 + 3][row] * L2E);
        *(float4*)(WtL + (size_t)(tc * 64 + row) * 512 + tr * 64 + lx * 4) = o;
    }
}

// ---- launch 2: partials + V-pack + x-transpose, role-split by blockIdx ----
__global__ __launch_bounds__(512) void k_mid(
        const float* __restrict__ x, const float* __restrict__ V,
        const float* __restrict__ WtL,
        unsigned short* __restrict__ VtA4, float* __restrict__ xt,
        float* __restrict__ A0) {
    __shared__ __align__(16) char smem[16640];
    const int blk = blockIdx.x;

    if (blk < 2048) {
        // A0[k][b][h] = sum_{d in chunk k} x[b,d]*WtL[d][h]  (verbatim k_partial)
        float* xs = (float*)smem;    // [32 d][8 b]
        const int k  = blk >> 6;
        const int bg = blk & 63;
        const int h  = threadIdx.x;
        const int d0 = k * DCv;
        if (threadIdx.x < DCv * 8) {
            int g = threadIdx.x >> 5;   // batch in group of 8
            int j = threadIdx.x & 31;   // d in chunk
            xs[j * 8 + g] = x[(size_t)(bg * 8 + g) * Dv + d0 + j];
        }
        __syncthreads();
        float acc[8];
#pragma unroll
        for (int g = 0; g < 8; ++g) acc[g] = 0.0f;
        const float* wp = WtL + (size_t)d0 * Hv + h;
        for (int j = 0; j < DCv; ++j) {
            float wv = wp[(size_t)j * Hv];
            const float4 x0 = *(const float4*)(xs + j * 8);
            const float4 x1 = *(const float4*)(xs + j * 8 + 4);
            acc[0] = fmaf(x0.x, wv, acc[0]);
            acc[1] = fmaf(x0.y, wv, acc[1]);
            acc[2] = fmaf(x0.z, wv, acc[2]);
            acc[3] = fmaf(x0.w, wv, acc[3]);
            acc[4] = fmaf(x1.x, wv, acc[4]);
            acc[5] = fmaf(x1.y, wv, acc[5]);
            acc[6] = fmaf(x1.z, wv, acc[6]);
            acc[7] = fmaf(x1.w, wv, acc[7]);
        }
#pragma unroll
        for (int g = 0; g < 8; ++g)
            A0[((size_t)k * Bv + bg * 8 + g) * Hv + h] = acc[g];
    } else if (blk < 2304) {
        // V -> VtA4 fragments (bf16 RNE), 4 d per block, 512-thread variant.
        // VtA4[((d*16 + hb)*16 + q*4 + c)*8 + j], elem = V[h=hb*32+q*8+j][d][c]
        unsigned short* tile = (unsigned short*)smem;   // 8192 shorts = 16 KiB
        const int d0  = (blk - 2048) * 4;
        const int dd  = threadIdx.x & 3;
        const int hb0 = threadIdx.x >> 2;   // 0..127 -> 128 h per pass
#pragma unroll
        for (int p = 0; p < 4; ++p) {
            int h = p * 128 + hb0;
            float4 v = *(const float4*)(V + ((size_t)h * Dv + d0 + dd) * Cv);
            int hb = h >> 5, q = (h >> 3) & 3, j = h & 7;
            int base = ((dd * 16 + hb) * 16 + q * 4) * 8 + j;
            tile[base + 0 * 8] = bf16rne(v.x);
            tile[base + 1 * 8] = bf16rne(v.y);
            tile[base + 2 * 8] = bf16rne(v.z);
            tile[base + 3 * 8] = bf16rne(v.w);
        }
        __syncthreads();
        uint4* dst = (uint4*)(VtA4 + (size_t)d0 * 2048);
        const uint4* srcp = (const uint4*)tile;
        for (int tt = threadIdx.x; tt < 1024; tt += 512) dst[tt] = srcp[tt];
    } else {
        // x -> xt transpose (scale 1), 512-thread variant of the 64x64 tile.
        float (*t)[65] = (float(*)[65])smem;
        const int tile = blk - 2304;         // 0..127
        const int tr   = tile >> 4;          // b tile
        const int tc   = tile & 15;          // d tile
        const int lx = threadIdx.x & 15;
        const int ly = threadIdx.x >> 4;     // 0..31
#pragma unroll
        for (int r = 0; r < 64; r += 32) {
            int row = r + ly;
            float4 v = *(const float4*)(x + (size_t)(tr * 64 + row) * Dv + tc * 64 + lx * 4);
            t[row][lx * 4 + 0] = v.x;
            t[row][lx * 4 + 1] = v.y;
            t[row][lx * 4 + 2] = v.z;
            t[row][lx * 4 + 3] = v.w;
        }
        __syncthreads();
#pragma unroll
        for (int r = 0; r < 64; r += 32) {
            int row = r + ly;   // d within tile
            float4 o = make_float4(t[lx * 4 + 0][row],
                                   t[lx * 4 + 1][row],
                                   t[lx * 4 + 2][row],
                                   t[lx * 4 + 3][row]);
            *(float4*)(xt + (size_t)(tc * 64 + row) * 512 + tr * 64 + lx * 4) = o;
        }
    }
}

// ---- launch 3: in-place exclusive prefix over chunks, seeded c*log2e ----
__global__ void k_prefix(float* __restrict__ A0, const float* __restrict__ cbias) {
    int gid = blockIdx.x * blockDim.x + threadIdx.x;   // B*H
    int h = gid & (Hv - 1);
    int bi = gid >> 9;
    float run = cbias[h] * L2E;
    float* p = A0 + (size_t)bi * Hv + h;
    for (int k = 0; k < Kv; ++k) {
        float t = p[(size_t)k * Bv * Hv];
        p[(size_t)k * Bv * Hv] = run;
        run += t;
    }
}

// ---- launch 4: main scan, OCT-step (8 d-steps per barrier). ----
__global__ __launch_bounds__(256, 4) void k_main(
        const float* __restrict__ xt, const float* __restrict__ bbias,
        const unsigned short* __restrict__ VtA4, const float* __restrict__ WtL,
        const float* __restrict__ A0, float* __restrict__ out) {
    const int k    = blockIdx.x >> 5;
    const int bg   = blockIdx.x & 31;
    const int wid  = threadIdx.x >> 6;   // H-slice owner
    const int lane = threadIdx.x & 63;
    const int bl   = lane & 15;          // batch col (B-op) / class row m (A-op)
    const int quad = lane >> 4;
    const int b    = bg * 16 + bl;
    const int d0   = k * DCv;

    // only quad==0 lanes carry nonzero C rows (classes 0..3) -> 16 batches/step
    __shared__ f32x4 red[2][8][4][16];   // [buf][step][wid][batch], 16 KiB

    // a state: h = wid*128 + kb*32 + quad*8 + j (scaled domain)
    float a[32];
    {
        const float* ap = A0 + ((size_t)k * Bv + b) * Hv + wid * 128 + quad * 8;
#pragma unroll
        for (int kb = 0; kb < 4; ++kb) {
            float4 t0 = *(const float4*)(ap + kb * 32);
            float4 t1 = *(const float4*)(ap + kb * 32 + 4);
            a[kb*8+0]=t0.x; a[kb*8+1]=t0.y; a[kb*8+2]=t0.z; a[kb*8+3]=t0.w;
            a[kb*8+4]=t1.x; a[kb*8+5]=t1.y; a[kb*8+6]=t1.z; a[kb*8+7]=t1.w;
        }
    }

    const bool act = (bl < 4);
    const unsigned short* vp = VtA4 + (((size_t)d0 * 16 + wid * 4) * 16 + quad * 4 + bl) * 8;
    const float* wp = WtL + (size_t)d0 * Hv + wid * 128 + quad * 8;
    const float* xp = xt + (size_t)d0 * Bv + b;

    // epilogue: wave wid finalizes steps {2wid, 2wid+1};
    // lanes 0-15 -> step 2wid, lanes 32-47 -> step 2wid+1.
    const int  sE  = wid * 2 + (lane >> 5);          // 0..7
    const bool epi = ((lane >> 4) & 1) == 0;         // quads 0 and 2
    const float* bpE = bbias + (d0 + sE) * Cv;
    float* spY = out + (size_t)b * Dv * Cv + (d0 + sE) * Cv;
    float* spP = spY + (size_t)Bv * Dv * Cv;

    const short8 zfrag = {0,0,0,0,0,0,0,0};

    for (int i1 = 0; i1 < DCv / 8; ++i1) {       // 4 iterations, 1 barrier each
        const int buf = i1 & 1;
#pragma unroll 1
        for (int half = 0; half < 2; ++half) {
#pragma unroll
            for (int s = 0; s < 4; ++s) {
                // this step's fragments + scalar (one step live at a time)
                short8 af[4];
#pragma unroll
                for (int kb = 0; kb < 4; ++kb)
                    af[kb] = act ? *(const short8*)(vp + s * 2048 + kb * 128) : zfrag;
                float xd = xp[s * Bv];

                // sigmoid + pack
                unsigned pk[16];
#pragma unroll
                for (int m = 0; m < 32; m += 2) {
                    float s0 = frcp(1.0f + fexp2(-a[m]));
                    float s1 = frcp(1.0f + fexp2(-a[m + 1]));
                    pk[m >> 1] = bf16pk(s0, s1);
                }
                // MFMA over the wave's 128-h slice
                f32x4 acc = {0.f, 0.f, 0.f, 0.f};
#pragma unroll
                for (int kb = 0; kb < 4; ++kb) {
                    union { unsigned u[4]; short8 s8; } cv;
                    cv.u[0] = pk[kb*4+0]; cv.u[1] = pk[kb*4+1];
                    cv.u[2] = pk[kb*4+2]; cv.u[3] = pk[kb*4+3];
                    acc = __builtin_amdgcn_mfma_f32_16x16x32_bf16(af[kb], cv.s8, acc, 0, 0, 0);
                }
                // advance a to next step (same fmaf sequence as R9)
#pragma unroll
                for (int kb = 0; kb < 4; ++kb)
#pragma unroll
                    for (int j = 0; j < 8; ++j)
                        a[kb*8+j] = fmaf(xd, wp[s * Hv + kb*32 + j], a[kb*8+j]);

                if (quad == 0) red[buf][half * 4 + s][wid][bl] = acc;
            }
            vp += 4 * 2048;
            wp += 4 * Hv;
            xp += 4 * Bv;
        }
        __syncthreads();

        // ---- epilogue: 8 steps finalized by 4 waves x 2 half-lane groups ----
        if (epi) {
            float4 bbv = *(const float4*)bpE;
            f32x4 r0 = red[buf][sE][0][bl];
            f32x4 r1 = red[buf][sE][1][bl];
            f32x4 r2 = red[buf][sE][2][bl];
            f32x4 r3 = red[buf][sE][3][bl];
            float w0 = r0.x + r1.x + r2.x + r3.x + bbv.x;
            float w1 = r0.y + r1.y + r2.y + r3.y + bbv.y;
            float w2 = r0.z + r1.z + r2.z + r3.z + bbv.z;
            float w3 = r0.w + r1.w + r2.w + r3.w + bbv.w;
            *(float4*)spY = make_float4(w0, w1, w2, w3);
            float mx = fmaxf(fmaxf(w0, w1), fmaxf(w2, w3));
            float e0 = fexp2((w0 - mx) * L2E);
            float e1 = fexp2((w1 - mx) * L2E);
            float e2 = fexp2((w2 - mx) * L2E);
            float e3 = fexp2((w3 - mx) * L2E);
            float lse = mx + flog2(e0 + e1 + e2 + e3) * LN2;
            *(float4*)spP = make_float4(w0 - lse, w1 - lse, w2 - lse, w3 - lse);
        }

        bpE += 8 * Cv;
        spY += 8 * Cv;
        spP += 8 * Cv;
    }
}

extern "C" void kernel_launch(void* const* d_in, const int* in_sizes, int n_in,
                              void* d_out, int out_size, void* d_ws, size_t ws_size,
                              hipStream_t stream) {
    const float* x  = (const float*)d_in[0];   // [B, D]
    const float* V  = (const float*)d_in[1];   // [H, D, C]
    const float* bb = (const float*)d_in[2];   // [D, C]
    const float* W  = (const float*)d_in[3];   // [H, D]
    const float* cb = (const float*)d_in[4];   // [1, H]
    float* out = (float*)d_out;                // y_hat [B*D*C] then p_hat

    char* ws = (char*)d_ws;
    unsigned short* VtA4 = (unsigned short*)ws;                 // 4 MiB
    float* WtL = (float*)(ws + (size_t)4 * 1024 * 1024);        // 2 MiB
    float* xt  = (float*)(ws + (size_t)6 * 1024 * 1024);        // 2 MiB
    float* A0  = (float*)(ws + (size_t)8 * 1024 * 1024);        // 32 MiB (K*B*H)

    k_prepW<<<128, 256, 0, stream>>>(W, WtL);
    k_mid<<<2432, 512, 0, stream>>>(x, V, WtL, VtA4, xt, A0);
    k_prefix<<<(Bv * Hv) / 256, 256, 0, stream>>>(A0, cb);
    k_main<<<Kv * 32, 256, 0, stream>>>(xt, bb, VtA4, WtL, A0, out);
}